// Round 3
// baseline (144.164 us; speedup 1.0000x reference)
//
#include <hip/hip_runtime.h>

#define Bsz 4
#define Nn  256
#define OBSD 40
#define ACTD 8
#define HEADS 8
#define DIMD 32
#define Td  256

// K1: emb = relu(relu(obs @ We1 + be1) @ We2 + be2)
// Blocks 0..7 additionally zero snh/shid (consumed by K2's atomics).
// grid = B*N blocks, 256 threads; one node-row per block.
__global__ void k_emb(const float* __restrict__ x,
                      const float* __restrict__ We1, const float* __restrict__ be1,
                      const float* __restrict__ We2, const float* __restrict__ be2,
                      float* __restrict__ emb,
                      float* __restrict__ snh, float* __restrict__ shid) {
    int row = blockIdx.x;              // b*N + n
    int b = row >> 8, n = row & 255;
    int t = threadIdx.x;               // output channel 0..255
    if (row < 4)      snh[row * Td + t] = 0.f;
    else if (row < 8) shid[(row - 4) * Td + t] = 0.f;
    __shared__ float obs_s[OBSD];
    __shared__ float h1[Td];
    if (t < OBSD) obs_s[t] = x[(b * (Nn + 1) + n) * OBSD + t];
    __syncthreads();
    float acc = be1[t];
#pragma unroll
    for (int k = 0; k < OBSD; ++k) acc = fmaf(obs_s[k], We1[k * Td + t], acc);
    h1[t] = fmaxf(acc, 0.f);
    __syncthreads();
    float acc2 = be2[t];
#pragma unroll 8
    for (int k = 0; k < Td; ++k) acc2 = fmaf(h1[k], We2[k * Td + t], acc2);
    emb[row * Td + t] = fmaxf(acc2, 0.f);
}

// K2 (fused ne + nh/hid reduction):
//   ne_row[t] = sum_n adj[m,n] * emb[b,n,t]          (no ne buffer materialized)
//   snh[b,t]  += relu(ne_row @ Wn + bn)[t]
//   shid[b,t] += relu(ne_row @ Wh + bh)[t]
__global__ void k_fused(const float* __restrict__ adj, const float* __restrict__ emb,
                        const float* __restrict__ Wn, const float* __restrict__ bn,
                        const float* __restrict__ Wh, const float* __restrict__ bh,
                        float* __restrict__ snh, float* __restrict__ shid) {
    int m = blockIdx.x, b = blockIdx.y;
    int t = threadIdx.x;
    __shared__ float arow[Nn];
    __shared__ float nrow[Td];
    arow[t] = adj[m * Nn + t];
    __syncthreads();
    const float* eb = emb + b * Nn * Td;
    float acc = 0.f;
#pragma unroll 8
    for (int n = 0; n < Nn; ++n) acc = fmaf(arow[n], eb[n * Td + t], acc);
    nrow[t] = acc;
    __syncthreads();
    float a1 = bn[t], a2 = bh[t];
#pragma unroll 4
    for (int k = 0; k < Td; ++k) {
        float v = nrow[k];
        a1 = fmaf(v, Wn[k * Td + t], a1);
        a2 = fmaf(v, Wh[k * Td + t], a2);
    }
    atomicAdd(&snh[b * Td + t], fmaxf(a1, 0.f));
    atomicAdd(&shid[b * Td + t], fmaxf(a2, 0.f));
}

// K3: per-batch target row -> ah -> softmax over DIM per head -> mean over heads -> Wa
__global__ void k_final(const float* __restrict__ x, const float* __restrict__ emb,
                        const float* __restrict__ Wl, const float* __restrict__ bl,
                        const float* __restrict__ snh, const float* __restrict__ shid,
                        const float* __restrict__ Wa, const float* __restrict__ ba,
                        float* __restrict__ out) {
    int b = blockIdx.x;
    int t = threadIdx.x;
    int tgt = (int)x[(b * (Nn + 1) + Nn) * OBSD + 0];
    tgt = tgt < 0 ? 0 : (tgt > Nn - 1 ? Nn - 1 : tgt);   // fault-proof
    __shared__ float erow[Td], lg[Td], p[Td], od[DIMD];
    erow[t] = emb[(b * Nn + tgt) * Td + t];
    __syncthreads();
    float acc = bl[t];
#pragma unroll 8
    for (int k = 0; k < Td; ++k) acc = fmaf(erow[k], Wl[k * Td + t], acc);
    float ah = fmaxf(acc, 0.f);
    lg[t] = ah * snh[b * Td + t];   // logit for (d = t>>3, h = t&7)
    __syncthreads();
    int h = t & 7;
    float mx = -1e30f;
#pragma unroll
    for (int d = 0; d < DIMD; ++d) mx = fmaxf(mx, lg[d * HEADS + h]);
    float se = 0.f;
#pragma unroll
    for (int d = 0; d < DIMD; ++d) se += __expf(lg[d * HEADS + h] - mx);
    float attn = __expf(lg[t] - mx) / se;
    p[t] = attn * shid[b * Td + t];
    __syncthreads();
    if (t < DIMD) {
        float s = 0.f;
#pragma unroll
        for (int hh = 0; hh < HEADS; ++hh) s += p[t * HEADS + hh];
        od[t] = s * (1.f / HEADS);
    }
    __syncthreads();
    if (t < ACTD) {
        float s = ba[t];
#pragma unroll
        for (int d = 0; d < DIMD; ++d) s = fmaf(od[d], Wa[d * ACTD + t], s);
        out[b * ACTD + t] = s;
    }
}

extern "C" void kernel_launch(void* const* d_in, const int* in_sizes, int n_in,
                              void* d_out, int out_size, void* d_ws, size_t ws_size,
                              hipStream_t stream) {
    const float* x   = (const float*)d_in[0];
    const float* adj = (const float*)d_in[1];
    const float* We1 = (const float*)d_in[2];
    const float* be1 = (const float*)d_in[3];
    const float* We2 = (const float*)d_in[4];
    const float* be2 = (const float*)d_in[5];
    const float* Wl  = (const float*)d_in[6];
    const float* bl  = (const float*)d_in[7];
    const float* Wn  = (const float*)d_in[8];
    const float* bn  = (const float*)d_in[9];
    const float* Wh  = (const float*)d_in[10];
    const float* bh  = (const float*)d_in[11];
    const float* Wa  = (const float*)d_in[12];
    const float* ba  = (const float*)d_in[13];
    float* out = (float*)d_out;

    // ws layout (total 1,056,768 bytes):
    //   emb  : f32[B*N*T] = 1048576 B
    //   snh  : f32[B*T]   =    4096 B
    //   shid : f32[B*T]   =    4096 B
    float* emb  = (float*)d_ws;
    float* snh  = emb + Bsz * Nn * Td;
    float* shid = snh + Bsz * Td;

    k_emb<<<dim3(Bsz * Nn), dim3(Td), 0, stream>>>(x, We1, be1, We2, be2, emb, snh, shid);
    k_fused<<<dim3(Nn, Bsz), dim3(Td), 0, stream>>>(adj, emb, Wn, bn, Wh, bh, snh, shid);
    k_final<<<dim3(Bsz), dim3(Td), 0, stream>>>(x, emb, Wl, bl, snh, shid, Wa, ba, out);
}

// Round 4
// 128.439 us; speedup vs baseline: 1.1224x; 1.1224x over previous
//
#include <hip/hip_runtime.h>

#define Bsz 4
#define Nn  256
#define OBSD 40
#define ACTD 8
#define HEADS 8
#define DIMD 32
#define Td  256
#define R   4   // rows per block (register blocking for weight reuse)

// K1: emb = relu(relu(obs @ We1 + be1) @ We2 + be2), R rows per block.
// Block 0/1 additionally zero snh/shid (consumed by K2's atomics).
// grid = B*N/R = 256 blocks, 256 threads (one output channel per thread).
__global__ void k_emb(const float* __restrict__ x,
                      const float* __restrict__ We1, const float* __restrict__ be1,
                      const float* __restrict__ We2, const float* __restrict__ be2,
                      float* __restrict__ emb,
                      float* __restrict__ snh, float* __restrict__ shid) {
    int g = blockIdx.x;                // row group: rows 4g..4g+3 (never crosses batch)
    int t = threadIdx.x;
    int row0 = g * R;
    int b = row0 >> 8;
    int n0 = row0 & 255;
    if (g == 0)      { for (int i = t; i < Bsz * Td; i += 256) snh[i]  = 0.f; }
    else if (g == 1) { for (int i = t; i < Bsz * Td; i += 256) shid[i] = 0.f; }

    __shared__ float4 obs_t[OBSD];     // obs_t[k] = {obs[row0+0][k], ..., obs[row0+3][k]}
    __shared__ float4 h1_t[Td];        // h1_t[k]  = hidden1 of the 4 rows at channel k
    if (t < R * OBSD) {
        int r = t & (R - 1), k = t >> 2;
        ((float*)&obs_t[k])[r] = x[(b * (Nn + 1) + n0 + r) * OBSD + k];
    }
    __syncthreads();

    float bias1 = be1[t];
    float acc[R] = {bias1, bias1, bias1, bias1};
#pragma unroll
    for (int k = 0; k < OBSD; ++k) {
        float w = We1[k * Td + t];
        float4 ov = obs_t[k];
        acc[0] = fmaf(ov.x, w, acc[0]);
        acc[1] = fmaf(ov.y, w, acc[1]);
        acc[2] = fmaf(ov.z, w, acc[2]);
        acc[3] = fmaf(ov.w, w, acc[3]);
    }
    h1_t[t] = make_float4(fmaxf(acc[0], 0.f), fmaxf(acc[1], 0.f),
                          fmaxf(acc[2], 0.f), fmaxf(acc[3], 0.f));
    __syncthreads();

    float bias2 = be2[t];
    float acc2[R] = {bias2, bias2, bias2, bias2};
#pragma unroll 8
    for (int k = 0; k < Td; ++k) {
        float w = We2[k * Td + t];
        float4 hv = h1_t[k];           // ds_read_b128 broadcast
        acc2[0] = fmaf(hv.x, w, acc2[0]);
        acc2[1] = fmaf(hv.y, w, acc2[1]);
        acc2[2] = fmaf(hv.z, w, acc2[2]);
        acc2[3] = fmaf(hv.w, w, acc2[3]);
    }
#pragma unroll
    for (int r = 0; r < R; ++r)
        emb[(row0 + r) * Td + t] = fmaxf(acc2[r], 0.f);
}

// K2 (fused ne + nh/hid reduction), R m-rows per block:
//   ne[r][t] = sum_n adj[m0+r,n] * emb[b,n,t]
//   snh[b,t]  += sum_r relu(ne[r] @ Wn + bn)[t]
//   shid[b,t] += sum_r relu(ne[r] @ Wh + bh)[t]
// grid = (N/R, B) = (64, 4), 256 threads.
__global__ void k_fused(const float* __restrict__ adj, const float* __restrict__ emb,
                        const float* __restrict__ Wn, const float* __restrict__ bn,
                        const float* __restrict__ Wh, const float* __restrict__ bh,
                        float* __restrict__ snh, float* __restrict__ shid) {
    int g = blockIdx.x, b = blockIdx.y;
    int t = threadIdx.x;
    int m0 = g * R;
    __shared__ float4 arow_t[Nn];      // arow_t[n] = {adj[m0+0][n], ..., adj[m0+3][n]}
    __shared__ float4 nrow_t[Td];      // nrow_t[k] = ne of the 4 rows at channel k
    arow_t[t] = make_float4(adj[(m0 + 0) * Nn + t], adj[(m0 + 1) * Nn + t],
                            adj[(m0 + 2) * Nn + t], adj[(m0 + 3) * Nn + t]);
    __syncthreads();

    const float* eb = emb + b * Nn * Td;
    float acc[R] = {0.f, 0.f, 0.f, 0.f};
#pragma unroll 8
    for (int n = 0; n < Nn; ++n) {
        float ev = eb[n * Td + t];
        float4 ar = arow_t[n];         // ds_read_b128 broadcast
        acc[0] = fmaf(ar.x, ev, acc[0]);
        acc[1] = fmaf(ar.y, ev, acc[1]);
        acc[2] = fmaf(ar.z, ev, acc[2]);
        acc[3] = fmaf(ar.w, ev, acc[3]);
    }
    nrow_t[t] = make_float4(acc[0], acc[1], acc[2], acc[3]);
    __syncthreads();

    float bn_t = bn[t], bh_t = bh[t];
    float s1[R] = {bn_t, bn_t, bn_t, bn_t};
    float s2[R] = {bh_t, bh_t, bh_t, bh_t};
#pragma unroll 8
    for (int k = 0; k < Td; ++k) {
        float4 nr = nrow_t[k];         // ds_read_b128 broadcast
        float wn = Wn[k * Td + t];
        float wh = Wh[k * Td + t];
        s1[0] = fmaf(nr.x, wn, s1[0]);  s2[0] = fmaf(nr.x, wh, s2[0]);
        s1[1] = fmaf(nr.y, wn, s1[1]);  s2[1] = fmaf(nr.y, wh, s2[1]);
        s1[2] = fmaf(nr.z, wn, s1[2]);  s2[2] = fmaf(nr.z, wh, s2[2]);
        s1[3] = fmaf(nr.w, wn, s1[3]);  s2[3] = fmaf(nr.w, wh, s2[3]);
    }
    float r1 = fmaxf(s1[0], 0.f) + fmaxf(s1[1], 0.f) + fmaxf(s1[2], 0.f) + fmaxf(s1[3], 0.f);
    float r2 = fmaxf(s2[0], 0.f) + fmaxf(s2[1], 0.f) + fmaxf(s2[2], 0.f) + fmaxf(s2[3], 0.f);
    atomicAdd(&snh[b * Td + t], r1);
    atomicAdd(&shid[b * Td + t], r2);
}

// K3: per-batch target row -> ah -> softmax over DIM per head -> mean over heads -> Wa
__global__ void k_final(const float* __restrict__ x, const float* __restrict__ emb,
                        const float* __restrict__ Wl, const float* __restrict__ bl,
                        const float* __restrict__ snh, const float* __restrict__ shid,
                        const float* __restrict__ Wa, const float* __restrict__ ba,
                        float* __restrict__ out) {
    int b = blockIdx.x;
    int t = threadIdx.x;
    int tgt = (int)x[(b * (Nn + 1) + Nn) * OBSD + 0];
    tgt = tgt < 0 ? 0 : (tgt > Nn - 1 ? Nn - 1 : tgt);   // fault-proof
    __shared__ float erow[Td], lg[Td], p[Td], od[DIMD];
    erow[t] = emb[(b * Nn + tgt) * Td + t];
    __syncthreads();
    float acc = bl[t];
#pragma unroll 8
    for (int k = 0; k < Td; ++k) acc = fmaf(erow[k], Wl[k * Td + t], acc);
    float ah = fmaxf(acc, 0.f);
    lg[t] = ah * snh[b * Td + t];   // logit for (d = t>>3, h = t&7)
    __syncthreads();
    int h = t & 7;
    float mx = -1e30f;
#pragma unroll
    for (int d = 0; d < DIMD; ++d) mx = fmaxf(mx, lg[d * HEADS + h]);
    float se = 0.f;
#pragma unroll
    for (int d = 0; d < DIMD; ++d) se += __expf(lg[d * HEADS + h] - mx);
    float attn = __expf(lg[t] - mx) / se;
    p[t] = attn * shid[b * Td + t];
    __syncthreads();
    if (t < DIMD) {
        float s = 0.f;
#pragma unroll
        for (int hh = 0; hh < HEADS; ++hh) s += p[t * HEADS + hh];
        od[t] = s * (1.f / HEADS);
    }
    __syncthreads();
    if (t < ACTD) {
        float s = ba[t];
#pragma unroll
        for (int d = 0; d < DIMD; ++d) s = fmaf(od[d], Wa[d * ACTD + t], s);
        out[b * ACTD + t] = s;
    }
}

extern "C" void kernel_launch(void* const* d_in, const int* in_sizes, int n_in,
                              void* d_out, int out_size, void* d_ws, size_t ws_size,
                              hipStream_t stream) {
    const float* x   = (const float*)d_in[0];
    const float* adj = (const float*)d_in[1];
    const float* We1 = (const float*)d_in[2];
    const float* be1 = (const float*)d_in[3];
    const float* We2 = (const float*)d_in[4];
    const float* be2 = (const float*)d_in[5];
    const float* Wl  = (const float*)d_in[6];
    const float* bl  = (const float*)d_in[7];
    const float* Wn  = (const float*)d_in[8];
    const float* bn  = (const float*)d_in[9];
    const float* Wh  = (const float*)d_in[10];
    const float* bh  = (const float*)d_in[11];
    const float* Wa  = (const float*)d_in[12];
    const float* ba  = (const float*)d_in[13];
    float* out = (float*)d_out;

    // ws layout: emb f32[B*N*T] (1 MB) | snh f32[B*T] | shid f32[B*T]
    float* emb  = (float*)d_ws;
    float* snh  = emb + Bsz * Nn * Td;
    float* shid = snh + Bsz * Td;

    k_emb<<<dim3(Bsz * Nn / R), dim3(Td), 0, stream>>>(x, We1, be1, We2, be2, emb, snh, shid);
    k_fused<<<dim3(Nn / R, Bsz), dim3(Td), 0, stream>>>(adj, emb, Wn, bn, Wh, bh, snh, shid);
    k_final<<<dim3(Bsz), dim3(Td), 0, stream>>>(x, emb, Wl, bl, snh, shid, Wa, ba, out);
}

// Round 5
// 109.297 us; speedup vs baseline: 1.3190x; 1.1751x over previous
//
#include <hip/hip_runtime.h>

#define Bsz 4
#define Nn  256
#define OBSD 40
#define ACTD 8
#define HEADS 8
#define DIMD 32
#define Td  256
#define R   4   // rows per block

#define FMA4(accr, s, wv) \
    (accr).x = fmaf((s), (wv).x, (accr).x); \
    (accr).y = fmaf((s), (wv).y, (accr).y); \
    (accr).z = fmaf((s), (wv).z, (accr).z); \
    (accr).w = fmaf((s), (wv).w, (accr).w)

// K1: emb = relu(relu(obs @ We1 + be1) @ We2 + be2), R=4 rows per block.
// Layer2: 4 waves k-split (64 iters each), float4 weight loads, LDS reduce.
// grid = B*N/R = 256 blocks, 256 threads.
__global__ void k_emb(const float* __restrict__ x,
                      const float* __restrict__ We1, const float* __restrict__ be1,
                      const float* __restrict__ We2, const float* __restrict__ be2,
                      float* __restrict__ emb,
                      float* __restrict__ snh, float* __restrict__ shid) {
    int g = blockIdx.x;
    int t = threadIdx.x;
    int row0 = g * R;
    int b = row0 >> 8;
    int n0 = row0 & 255;
    if (g == 0)      { for (int i = t; i < Bsz * Td; i += 256) snh[i]  = 0.f; }
    else if (g == 1) { for (int i = t; i < Bsz * Td; i += 256) shid[i] = 0.f; }

    __shared__ float4 obs_t[OBSD];        // obs_t[k] = 4 rows at obs-channel k
    __shared__ float4 h1_t[Td];           // h1_t[k]  = 4 rows at hidden channel k
    __shared__ float4 part[4][R][64];     // [wave][row][colgroup] partials (16 KB)
    if (t < R * OBSD) {
        int r = t & (R - 1), k = t >> 2;
        ((float*)&obs_t[k])[r] = x[(b * (Nn + 1) + n0 + r) * OBSD + k];
    }
    __syncthreads();

    // Layer 1 (K=40, cheap): thread t owns column t for all 4 rows.
    float bias1 = be1[t];
    float a1[R] = {bias1, bias1, bias1, bias1};
#pragma unroll
    for (int k = 0; k < OBSD; ++k) {
        float w = We1[k * Td + t];
        float4 ov = obs_t[k];
        a1[0] = fmaf(ov.x, w, a1[0]);
        a1[1] = fmaf(ov.y, w, a1[1]);
        a1[2] = fmaf(ov.z, w, a1[2]);
        a1[3] = fmaf(ov.w, w, a1[3]);
    }
    h1_t[t] = make_float4(fmaxf(a1[0], 0.f), fmaxf(a1[1], 0.f),
                          fmaxf(a1[2], 0.f), fmaxf(a1[3], 0.f));
    __syncthreads();

    // Layer 2: wave wv handles k in [64*wv, 64*wv+64); lane c owns cols 4c..4c+3.
    int wv = t >> 6, c = t & 63;
    float4 a2[R] = {};
#pragma unroll 8
    for (int i = 0; i < 64; ++i) {
        int k = (wv << 6) + i;
        float4 wvv = *(const float4*)(We2 + k * Td + 4 * c);
        float4 hv = h1_t[k];
        FMA4(a2[0], hv.x, wvv);
        FMA4(a2[1], hv.y, wvv);
        FMA4(a2[2], hv.z, wvv);
        FMA4(a2[3], hv.w, wvv);
    }
#pragma unroll
    for (int r = 0; r < R; ++r) part[wv][r][c] = a2[r];
    __syncthreads();

    // Cross-wave reduce: thread t owns column t.
    int c2 = t >> 2, j = t & 3;
#pragma unroll
    for (int r = 0; r < R; ++r) {
        float v = be2[t];
#pragma unroll
        for (int w2 = 0; w2 < 4; ++w2) v += ((const float*)&part[w2][r][c2])[j];
        emb[(row0 + r) * Td + t] = fmaxf(v, 0.f);
    }
}

// K2 (fused ne + Wn/Wh reduction), R=4 m-rows per block, same k-split template.
// grid = (N/R, B) = (64, 4), 256 threads.
__global__ void k_fused(const float* __restrict__ adj, const float* __restrict__ emb,
                        const float* __restrict__ Wn, const float* __restrict__ bn,
                        const float* __restrict__ Wh, const float* __restrict__ bh,
                        float* __restrict__ snh, float* __restrict__ shid) {
    int g = blockIdx.x, b = blockIdx.y;
    int t = threadIdx.x;
    int m0 = g * R;
    __shared__ float4 arow_t[Nn];         // arow_t[n] = adj rows m0..m0+3 at col n
    __shared__ float4 nrow_t[Td];         // nrow_t[k] = ne of the 4 rows at channel k
    __shared__ float4 partN[4][R][64];    // 16 KB
    __shared__ float4 partH[4][R][64];    // 16 KB
    arow_t[t] = make_float4(adj[(m0 + 0) * Nn + t], adj[(m0 + 1) * Nn + t],
                            adj[(m0 + 2) * Nn + t], adj[(m0 + 3) * Nn + t]);
    __syncthreads();

    int wv = t >> 6, c = t & 63;
    const float* eb = emb + b * Nn * Td;

    // ne: wave wv sums n in [64*wv, +64); lane c owns cols 4c..4c+3.
    float4 aN[R] = {};
#pragma unroll 8
    for (int i = 0; i < 64; ++i) {
        int n = (wv << 6) + i;
        float4 ev = *(const float4*)(eb + n * Td + 4 * c);
        float4 ar = arow_t[n];
        FMA4(aN[0], ar.x, ev);
        FMA4(aN[1], ar.y, ev);
        FMA4(aN[2], ar.z, ev);
        FMA4(aN[3], ar.w, ev);
    }
#pragma unroll
    for (int r = 0; r < R; ++r) partN[wv][r][c] = aN[r];
    __syncthreads();

    int c2 = t >> 2, j = t & 3;
    {
        float nr[R];
#pragma unroll
        for (int r = 0; r < R; ++r) {
            float v = 0.f;
#pragma unroll
            for (int w2 = 0; w2 < 4; ++w2) v += ((const float*)&partN[w2][r][c2])[j];
            nr[r] = v;
        }
        nrow_t[t] = make_float4(nr[0], nr[1], nr[2], nr[3]);
    }
    __syncthreads();

    // Wn/Wh: wave wv handles k in [64*wv, +64); 32 acc chains.
    float4 sN[R] = {};
    float4 sH[R] = {};
#pragma unroll 4
    for (int i = 0; i < 64; ++i) {
        int k = (wv << 6) + i;
        float4 nv = nrow_t[k];
        float4 wnv = *(const float4*)(Wn + k * Td + 4 * c);
        float4 whv = *(const float4*)(Wh + k * Td + 4 * c);
        FMA4(sN[0], nv.x, wnv);  FMA4(sH[0], nv.x, whv);
        FMA4(sN[1], nv.y, wnv);  FMA4(sH[1], nv.y, whv);
        FMA4(sN[2], nv.z, wnv);  FMA4(sH[2], nv.z, whv);
        FMA4(sN[3], nv.w, wnv);  FMA4(sH[3], nv.w, whv);
    }
#pragma unroll
    for (int r = 0; r < R; ++r) { partN[wv][r][c] = sN[r]; partH[wv][r][c] = sH[r]; }
    __syncthreads();

    // Reduce over waves (pre-relu), add bias, relu, sum over the 4 m-rows, atomic.
    float bnt = bn[t], bht = bh[t];
    float rs1 = 0.f, rs2 = 0.f;
#pragma unroll
    for (int r = 0; r < R; ++r) {
        float v1 = bnt, v2 = bht;
#pragma unroll
        for (int w2 = 0; w2 < 4; ++w2) {
            v1 += ((const float*)&partN[w2][r][c2])[j];
            v2 += ((const float*)&partH[w2][r][c2])[j];
        }
        rs1 += fmaxf(v1, 0.f);
        rs2 += fmaxf(v2, 0.f);
    }
    atomicAdd(&snh[b * Td + t], rs1);
    atomicAdd(&shid[b * Td + t], rs2);
}

// K3: per-batch target row -> ah -> softmax over DIM per head -> mean -> Wa
__global__ void k_final(const float* __restrict__ x, const float* __restrict__ emb,
                        const float* __restrict__ Wl, const float* __restrict__ bl,
                        const float* __restrict__ snh, const float* __restrict__ shid,
                        const float* __restrict__ Wa, const float* __restrict__ ba,
                        float* __restrict__ out) {
    int b = blockIdx.x;
    int t = threadIdx.x;
    int tgt = (int)x[(b * (Nn + 1) + Nn) * OBSD + 0];
    tgt = tgt < 0 ? 0 : (tgt > Nn - 1 ? Nn - 1 : tgt);
    __shared__ float erow[Td], lg[Td], p[Td], od[DIMD];
    __shared__ float4 partL[4][64];
    erow[t] = emb[(b * Nn + tgt) * Td + t];
    __syncthreads();

    int wv = t >> 6, c = t & 63;
    float4 aL = {};
#pragma unroll 8
    for (int i = 0; i < 64; ++i) {
        int k = (wv << 6) + i;
        float4 wlv = *(const float4*)(Wl + k * Td + 4 * c);
        FMA4(aL, erow[k], wlv);
    }
    partL[wv][c] = aL;
    __syncthreads();

    int c2 = t >> 2, j = t & 3;
    float acc = bl[t];
#pragma unroll
    for (int w2 = 0; w2 < 4; ++w2) acc += ((const float*)&partL[w2][c2])[j];
    float ah = fmaxf(acc, 0.f);
    lg[t] = ah * snh[b * Td + t];   // logit for (d = t>>3, h = t&7)
    __syncthreads();
    int h = t & 7;
    float mx = -1e30f;
#pragma unroll
    for (int d = 0; d < DIMD; ++d) mx = fmaxf(mx, lg[d * HEADS + h]);
    float se = 0.f;
#pragma unroll
    for (int d = 0; d < DIMD; ++d) se += __expf(lg[d * HEADS + h] - mx);
    float attn = __expf(lg[t] - mx) / se;
    p[t] = attn * shid[b * Td + t];
    __syncthreads();
    if (t < DIMD) {
        float s = 0.f;
#pragma unroll
        for (int hh = 0; hh < HEADS; ++hh) s += p[t * HEADS + hh];
        od[t] = s * (1.f / HEADS);
    }
    __syncthreads();
    if (t < ACTD) {
        float s = ba[t];
#pragma unroll
        for (int d = 0; d < DIMD; ++d) s = fmaf(od[d], Wa[d * ACTD + t], s);
        out[b * ACTD + t] = s;
    }
}

extern "C" void kernel_launch(void* const* d_in, const int* in_sizes, int n_in,
                              void* d_out, int out_size, void* d_ws, size_t ws_size,
                              hipStream_t stream) {
    const float* x   = (const float*)d_in[0];
    const float* adj = (const float*)d_in[1];
    const float* We1 = (const float*)d_in[2];
    const float* be1 = (const float*)d_in[3];
    const float* We2 = (const float*)d_in[4];
    const float* be2 = (const float*)d_in[5];
    const float* Wl  = (const float*)d_in[6];
    const float* bl  = (const float*)d_in[7];
    const float* Wn  = (const float*)d_in[8];
    const float* bn  = (const float*)d_in[9];
    const float* Wh  = (const float*)d_in[10];
    const float* bh  = (const float*)d_in[11];
    const float* Wa  = (const float*)d_in[12];
    const float* ba  = (const float*)d_in[13];
    float* out = (float*)d_out;

    // ws layout: emb f32[B*N*T] (1 MB) | snh f32[B*T] | shid f32[B*T]
    float* emb  = (float*)d_ws;
    float* snh  = emb + Bsz * Nn * Td;
    float* shid = snh + Bsz * Td;

    k_emb<<<dim3(Bsz * Nn / R), dim3(Td), 0, stream>>>(x, We1, be1, We2, be2, emb, snh, shid);
    k_fused<<<dim3(Nn / R, Bsz), dim3(Td), 0, stream>>>(adj, emb, Wn, bn, Wh, bh, snh, shid);
    k_final<<<dim3(Bsz), dim3(Td), 0, stream>>>(x, emb, Wl, bl, snh, shid, Wa, ba, out);
}